// Round 6
// baseline (3823.196 us; speedup 1.0000x reference)
//
#include <hip/hip_runtime.h>
#include <stdint.h>

// Persistent-kernel RNN, R6 = R3 skeleton + verified XCD-local sync scope.
// W_hh bf16 resident in registers (fB, 128 VGPR/wave). h exchanged via
// per-bg-group flags; if all 16 peers of a group verify same XCC_ID, the
// group's h/flag traffic runs at XCD scope (sc0 = agent/L2) instead of
// device scope (sc0 sc1 = IC) -> ~3x lower sync latency, no HBM write-through.
// Non-local groups fall back to the proven R3 device-scope protocol.

#define BATCH 512
#define SEQ   256
#define HID   1024
#define CLS   128

#define GB 16
#define GJ 16
#define BT 32
#define JT 64
#define WSTR 1028
#define SSTR 1032
#define HSTR 72
#define SMEM_BYTES (JT * WSTR * 2)                 // 131584 B
#define SS_BYTES   (BT * SSTR * 2)                 // 66048
#define RB_OFF     SS_BYTES
#define HS_OFF     (RB_OFF + 8192)
#define HBUF_HALVES (BATCH * HID)                  // 1 MB per buffer (x2)

typedef __attribute__((ext_vector_type(8))) short  bf16x8;
typedef __attribute__((ext_vector_type(4))) short  s16x4;
typedef __attribute__((ext_vector_type(4))) float  f32x4;
typedef __attribute__((ext_vector_type(4))) int    i32x4;

__device__ __forceinline__ unsigned short f2bf(float f) {
  unsigned int u = __float_as_uint(f);
  u = (u + 0x7FFFu + ((u >> 16) & 1u)) >> 16;   // RNE
  return (unsigned short)u;
}
__device__ __forceinline__ float b2f(short h) {
  return __uint_as_float(((unsigned int)(unsigned short)h) << 16);
}

// ---------------- scoped memory ops ----------------
// LP=true : XCD (agent) scope: sc0 only (L2 coherence point, bypass L1).
// LP=false: device scope: sc0 sc1 (IC coherence point).
template<bool LP>
__device__ __forceinline__ void g_store_flag(int* p, int v) {
  if constexpr (LP)
    asm volatile("global_store_dword %0, %1, off sc0" :: "v"(p), "v"(v) : "memory");
  else
    asm volatile("global_store_dword %0, %1, off sc0 sc1" :: "v"(p), "v"(v) : "memory");
}
template<bool LP>
__device__ __forceinline__ void g_store16(void* p, i32x4 v) {
  if constexpr (LP)
    asm volatile("global_store_dwordx4 %0, %1, off sc0" :: "v"(p), "v"(v) : "memory");
  else
    asm volatile("global_store_dwordx4 %0, %1, off sc0 sc1" :: "v"(p), "v"(v) : "memory");
}
template<bool LP>
__device__ __forceinline__ void g_issue4(const void* p, i32x4& a, i32x4& b, i32x4& c, i32x4& d) {
  if constexpr (LP)
    asm volatile(
      "global_load_dwordx4 %0, %4, off sc0\n\t"
      "global_load_dwordx4 %1, %4, off offset:128 sc0\n\t"
      "global_load_dwordx4 %2, %4, off offset:256 sc0\n\t"
      "global_load_dwordx4 %3, %4, off offset:384 sc0"
      : "=&v"(a), "=&v"(b), "=&v"(c), "=&v"(d) : "v"(p) : "memory");
  else
    asm volatile(
      "global_load_dwordx4 %0, %4, off sc0 sc1\n\t"
      "global_load_dwordx4 %1, %4, off offset:128 sc0 sc1\n\t"
      "global_load_dwordx4 %2, %4, off offset:256 sc0 sc1\n\t"
      "global_load_dwordx4 %3, %4, off offset:384 sc0 sc1"
      : "=&v"(a), "=&v"(b), "=&v"(c), "=&v"(d) : "v"(p) : "memory");
}
// min of 16 peer flags in one round trip (one 64B line)
template<bool LP>
__device__ __forceinline__ int flags_min16(const int* p) {
  i32x4 f0, f1, f2, f3;
  if constexpr (LP)
    asm volatile(
      "global_load_dwordx4 %0, %4, off sc0\n\t"
      "global_load_dwordx4 %1, %4, off offset:16 sc0\n\t"
      "global_load_dwordx4 %2, %4, off offset:32 sc0\n\t"
      "global_load_dwordx4 %3, %4, off offset:48 sc0\n\t"
      "s_waitcnt vmcnt(0)"
      : "=&v"(f0), "=&v"(f1), "=&v"(f2), "=&v"(f3) : "v"(p) : "memory");
  else
    asm volatile(
      "global_load_dwordx4 %0, %4, off sc0 sc1\n\t"
      "global_load_dwordx4 %1, %4, off offset:16 sc0 sc1\n\t"
      "global_load_dwordx4 %2, %4, off offset:32 sc0 sc1\n\t"
      "global_load_dwordx4 %3, %4, off offset:48 sc0 sc1\n\t"
      "s_waitcnt vmcnt(0)"
      : "=&v"(f0), "=&v"(f1), "=&v"(f2), "=&v"(f3) : "v"(p) : "memory");
  int m = f0.x;
  m = f0.y < m ? f0.y : m;  m = f0.z < m ? f0.z : m;  m = f0.w < m ? f0.w : m;
  m = f1.x < m ? f1.x : m;  m = f1.y < m ? f1.y : m;  m = f1.z < m ? f1.z : m;  m = f1.w < m ? f1.w : m;
  m = f2.x < m ? f2.x : m;  m = f2.y < m ? f2.y : m;  m = f2.z < m ? f2.z : m;  m = f2.w < m ? f2.w : m;
  m = f3.x < m ? f3.x : m;  m = f3.y < m ? f3.y : m;  m = f3.z < m ? f3.z : m;  m = f3.w < m ? f3.w : m;
  return m;
}
// device-scope min+max over a 16-int line (XCC-exchange only)
__device__ __forceinline__ void flags_minmax16_dev(const int* p, int& mn, int& mx) {
  i32x4 f0, f1, f2, f3;
  asm volatile(
    "global_load_dwordx4 %0, %4, off sc0 sc1\n\t"
    "global_load_dwordx4 %1, %4, off offset:16 sc0 sc1\n\t"
    "global_load_dwordx4 %2, %4, off offset:32 sc0 sc1\n\t"
    "global_load_dwordx4 %3, %4, off offset:48 sc0 sc1\n\t"
    "s_waitcnt vmcnt(0)"
    : "=&v"(f0), "=&v"(f1), "=&v"(f2), "=&v"(f3) : "v"(p) : "memory");
  int a[16] = {f0.x,f0.y,f0.z,f0.w, f1.x,f1.y,f1.z,f1.w,
               f2.x,f2.y,f2.z,f2.w, f3.x,f3.y,f3.z,f3.w};
  mn = a[0]; mx = a[0];
#pragma unroll
  for (int i = 1; i < 16; ++i) { mn = a[i] < mn ? a[i] : mn; mx = a[i] > mx ? a[i] : mx; }
}
__device__ __forceinline__ void store_flag_dev(int* p, int v) {
  asm volatile("global_store_dword %0, %1, off sc0 sc1" :: "v"(p), "v"(v) : "memory");
}
__device__ __forceinline__ void waitcnt0() {
  asm volatile("s_waitcnt vmcnt(0)" ::: "memory");
}
__device__ __forceinline__ void barrier_lgkm() {
  asm volatile("s_waitcnt lgkmcnt(0)\n\ts_barrier" ::: "memory");
}
#define DEF_WAIT(NAME, N) \
__device__ __forceinline__ void NAME(i32x4& a, i32x4& b, i32x4& c, i32x4& d) { \
  asm volatile("s_waitcnt vmcnt(" #N ")" : "+v"(a), "+v"(b), "+v"(c), "+v"(d) :: "memory"); \
}
DEF_WAIT(wait_vm12, 12)
DEF_WAIT(wait_vm8, 8)
DEF_WAIT(wait_vm4, 4)
DEF_WAIT(wait_vm0, 0)

__device__ __forceinline__ void wr16(short* p, i32x4 v) {
  union { i32x4 i; bf16x8 v8; } u; u.i = v;
  *(bf16x8*)p = u.v8;
}
__device__ __forceinline__ float tanh_fast(float z) {
  float e = __expf(2.f * z);
  return 1.f - 2.f / (e + 1.f);
}

template<int CK>
__device__ __forceinline__ void mfma_chunk(const short* sA0, const bf16x8 (&fB)[2][16],
                                           f32x4 (&acc)[2][2]) {
#pragma unroll
  for (int ks = 0; ks < 8; ++ks) {
    const int kk = CK * 8 + ks;
    bf16x8 a0 = *(const bf16x8*)(sA0 + CK * 256 + ks * 32);
    bf16x8 a1 = *(const bf16x8*)(sA0 + 16 * SSTR + CK * 256 + ks * 32);
#pragma unroll
    for (int nt = 0; nt < 2; ++nt) {
      acc[0][nt] = __builtin_amdgcn_mfma_f32_16x16x32_bf16(a0, fB[nt][kk], acc[0][nt], 0, 0, 0);
      acc[1][nt] = __builtin_amdgcn_mfma_f32_16x16x32_bf16(a1, fB[nt][kk], acc[1][nt], 0, 0, 0);
    }
  }
}

// poll peers' flags until >= t. Local mode: capped sc0 polls, then device-scope
// fallback (liveness insurance; stores are scope-matched so data is valid).
template<bool LP>
__device__ __forceinline__ void spin_flags(const int* myflags, int t) {
  if constexpr (LP) {
    int tries = 0;
    for (;;) {
      if (flags_min16<true>(myflags) >= t) return;
      if (++tries >= 64) break;
    }
    while (flags_min16<false>(myflags) < t) {}
  } else {
    while (flags_min16<false>(myflags) < t) {}
  }
}

// ---------------- recurrence + head, scope-templated (R3 body) ----------------
template<bool LP>
__device__ __forceinline__ void rnn_body(
    const float* __restrict__ x, const float* __restrict__ Wph,
    const float* __restrict__ bp, float* __restrict__ out,
    unsigned short* hbuf, int* myflags,
    short* sS, float* rbuf, short* hS,
    const bf16x8 (&fB)[2][16],
    int tid, int bg, int jg, int lane, int npair, int khalf,
    int l15, int quad,
    float whx0, float whx1, float bh0, float bh1,
    int sr, int seg)
{
  const short* sA0 = sS + l15 * SSTR + khalf * 512 + quad * 8;

  for (int t = 0; t < SEQ; ++t) {
    const unsigned short* hin = hbuf + ((t + 1) & 1) * HBUF_HALVES;
    unsigned short*      hout = hbuf + (t & 1) * HBUF_HALVES;

    f32x4 acc[2][2];
#pragma unroll
    for (int mt = 0; mt < 2; ++mt)
#pragma unroll
      for (int nt = 0; nt < 2; ++nt)
        acc[mt][nt] = (f32x4){0.f, 0.f, 0.f, 0.f};

    float xv[2][4];
    {
      const float* xp = x + (bg * BT + quad * 4) * SEQ + t;
#pragma unroll
      for (int r = 0; r < 4; ++r) {
        xv[0][r] = xp[r * SEQ];
        xv[1][r] = xp[(16 + r) * SEQ];
      }
    }

    if (t > 0) {
      if (tid == 0) spin_flags<LP>(myflags, t);
      __syncthreads();   // full drain: vmcnt==0 entering the issue window

      const char* lbase = (const char*)(hin + (bg * BT + sr) * HID) + seg * 16;
      short* sdst = sS + sr * SSTR + seg * 8;

      i32x4 a0, a1, a2, a3, b0, b1, b2, b3, c0, c1, c2, c3, d0, d1, d2, d3;
      g_issue4<LP>(lbase,        a0, a1, a2, a3);
      g_issue4<LP>(lbase + 512,  b0, b1, b2, b3);
      g_issue4<LP>(lbase + 1024, c0, c1, c2, c3);
      g_issue4<LP>(lbase + 1536, d0, d1, d2, d3);

      wait_vm12(a0, a1, a2, a3);
      wr16(sdst, a0); wr16(sdst + 64, a1); wr16(sdst + 128, a2); wr16(sdst + 192, a3);
      barrier_lgkm();
      if (khalf == 0) mfma_chunk<0>(sA0, fB, acc);

      wait_vm8(b0, b1, b2, b3);
      wr16(sdst + 256, b0); wr16(sdst + 320, b1); wr16(sdst + 384, b2); wr16(sdst + 448, b3);
      barrier_lgkm();
      if (khalf == 0) mfma_chunk<1>(sA0, fB, acc);

      wait_vm4(c0, c1, c2, c3);
      wr16(sdst + 512, c0); wr16(sdst + 576, c1); wr16(sdst + 640, c2); wr16(sdst + 704, c3);
      barrier_lgkm();
      if (khalf == 1) mfma_chunk<0>(sA0, fB, acc);

      wait_vm0(d0, d1, d2, d3);
      wr16(sdst + 768, d0); wr16(sdst + 832, d1); wr16(sdst + 896, d2); wr16(sdst + 960, d3);
      barrier_lgkm();
      if (khalf == 1) mfma_chunk<1>(sA0, fB, acc);
    }

    // cross-wave k-reduce: khalf==1 writes partials, khalf==0 adds + epilogue
    if (khalf == 1) {
#pragma unroll
      for (int mt = 0; mt < 2; ++mt)
#pragma unroll
        for (int nt = 0; nt < 2; ++nt)
          *(f32x4*)(rbuf + ((npair * 4 + mt * 2 + nt) * 64 + lane) * 4) = acc[mt][nt];
    }
    barrier_lgkm();

    if (khalf == 0) {
#pragma unroll
      for (int mt = 0; mt < 2; ++mt)
#pragma unroll
        for (int nt = 0; nt < 2; ++nt) {
          f32x4 p = *(const f32x4*)(rbuf + ((npair * 4 + mt * 2 + nt) * 64 + lane) * 4);
          acc[mt][nt] += p;
        }
#pragma unroll
      for (int mt = 0; mt < 2; ++mt) {
#pragma unroll
        for (int r = 0; r < 4; ++r) {
          const int row = mt * 16 + quad * 4 + r;
          float z0 = acc[mt][0][r] + xv[mt][r] * whx0 + bh0;
          hS[row * HSTR + npair * 32 + l15] = (short)f2bf(tanh_fast(z0));
          float z1 = acc[mt][1][r] + xv[mt][r] * whx1 + bh1;
          hS[row * HSTR + npair * 32 + 16 + l15] = (short)f2bf(tanh_fast(z1));
        }
      }
    }
    barrier_lgkm();

    // coalesced 16B store of the 32x64 h tile (scope-matched)
    {
      union { bf16x8 v8; i32x4 i; } u;
      u.v8 = *(const bf16x8*)(hS + sr * HSTR + seg * 8);
      g_store16<LP>(hout + (bg * BT + sr) * HID + jg * JT + seg * 8, u.i);
    }
    waitcnt0();          // acked at the scope's coherence point (L2 or IC)
    barrier_lgkm();
    if (tid == 0) g_store_flag<LP>(myflags + jg, t + 1);
  }

  // ---- output head ----
  if (tid == 0) spin_flags<LP>(myflags, SEQ);
  __syncthreads();

  const unsigned short* hlast = hbuf + ((SEQ - 1) & 1) * HBUF_HALVES;
  {
    const char* lbase = (const char*)(hlast + (bg * BT + sr) * HID) + seg * 16;
    short* sdst = sS + sr * SSTR + seg * 8;
    i32x4 p0, p1, p2, p3;
#pragma unroll
    for (int c = 0; c < 4; ++c) {
      g_issue4<LP>(lbase + c * 512, p0, p1, p2, p3);
      waitcnt0();
      wr16(sdst + c * 256, p0); wr16(sdst + c * 256 + 64, p1);
      wr16(sdst + c * 256 + 128, p2); wr16(sdst + c * 256 + 192, p3);
    }
  }
  __syncthreads();

  {
    const int cg = jg * 8 + (tid & 7);
    const int hr = tid >> 3;
    float acc = 0.f;
    const float* wp = Wph + cg * HID;
    const short* hs = sS + hr * SSTR;
#pragma unroll 8
    for (int k4 = 0; k4 < 256; ++k4) {
      float4 w  = *(const float4*)(wp + k4 * 4);
      s16x4 hv  = *(const s16x4*)(hs + k4 * 4);
      acc += b2f(hv.x) * w.x + b2f(hv.y) * w.y + b2f(hv.z) * w.z + b2f(hv.w) * w.w;
    }
    out[(bg * BT + hr) * CLS + cg] = acc + bp[cg];
  }
}

__global__ void __launch_bounds__(256, 1)
rnn_persistent(const float* __restrict__ x, const float* __restrict__ Whx,
               const float* __restrict__ Whh, const float* __restrict__ bh,
               const float* __restrict__ Wph, const float* __restrict__ bp,
               float* __restrict__ out, unsigned short* hbuf, int* flags)
{
  extern __shared__ short smem[];
  short* sW   = smem;
  short* sS   = smem;
  float* rbuf = (float*)((char*)smem + RB_OFF);
  short* hS   = (short*)((char*)smem + HS_OFF);
  __shared__ int s_local;

  const int tid  = threadIdx.x;
  const int bg   = blockIdx.x & 15;
  const int jg   = blockIdx.x >> 4;
  const int lane = tid & 63;
  const int wv   = tid >> 6;
  const int l15  = lane & 15;
  const int quad = lane >> 4;
  const int npair = wv & 1;
  const int khalf = wv >> 1;

  // flag line layout (proven ws envelope: 2 MB + 4 KB total):
  // ints [0,16)  of line bg*64 : step flags
  // ints [16,32) of line bg*64 : XCC-id exchange
  int* myflags = flags + bg * 64;
  int* xline   = myflags + 16;

  // ---- post my XCC id (device scope, once) ----
  if (tid == 0) {
    int xcd;
    asm volatile("s_getreg_b32 %0, hwreg(HW_REG_XCC_ID)" : "=s"(xcd));
    store_flag_dev(xline + jg, 4096 + xcd);
  }

  // ---- stage W_hh slice into LDS as bf16 (init only) ----
  {
    const int jr = tid >> 2;
    const int kq = tid & 3;
    const float* src = Whh + (jg * JT + jr) * HID + kq * 256;
    short* dst = sW + jr * WSTR + kq * 256;
#pragma unroll 4
    for (int i = 0; i < 64; ++i) {
      float4 f = *(const float4*)(src + i * 4);
      s16x4 h4;
      h4.x = (short)f2bf(f.x); h4.y = (short)f2bf(f.y);
      h4.z = (short)f2bf(f.z); h4.w = (short)f2bf(f.w);
      *(s16x4*)(dst + i * 4) = h4;
    }
  }
  __syncthreads();

  // ---- preload B-fragments into registers (128 VGPR/wave) ----
  bf16x8 fB[2][16];
#pragma unroll
  for (int nt = 0; nt < 2; ++nt) {
    const short* bp_ = sW + (npair * 32 + nt * 16 + l15) * WSTR + khalf * 512 + quad * 8;
#pragma unroll
    for (int kk = 0; kk < 16; ++kk) {
      union { bf16x8 v8; s16x4 h[2]; } u;
      u.h[0] = *(const s16x4*)(bp_ + kk * 32);
      u.h[1] = *(const s16x4*)(bp_ + kk * 32 + 4);
      fB[nt][kk] = u.v8;
    }
  }

  // ---- finish XCC exchange: whole bg-group on one XCD? ----
  if (tid == 0) {
    int mn, mx;
    do { flags_minmax16_dev(xline, mn, mx); } while (mn < 4096);
    s_local = (mn == mx) ? 1 : 0;
  }
  __syncthreads();   // also covers sW -> sS overlay transition
  const bool local = (s_local != 0);

  const int jb0 = jg * JT + npair * 32;
  const float whx0 = Whx[jb0 + l15];
  const float whx1 = Whx[jb0 + 16 + l15];
  const float bh0  = bh[jb0 + l15];
  const float bh1  = bh[jb0 + 16 + l15];
  const int sr  = tid >> 3;
  const int seg = tid & 7;

  if (local)
    rnn_body<true>(x, Wph, bp, out, hbuf, myflags, sS, rbuf, hS, fB,
                   tid, bg, jg, lane, npair, khalf, l15, quad,
                   whx0, whx1, bh0, bh1, sr, seg);
  else
    rnn_body<false>(x, Wph, bp, out, hbuf, myflags, sS, rbuf, hS, fB,
                    tid, bg, jg, lane, npair, khalf, l15, quad,
                    whx0, whx1, bh0, bh1, sr, seg);
}

extern "C" void kernel_launch(void* const* d_in, const int* in_sizes, int n_in,
                              void* d_out, int out_size, void* d_ws, size_t ws_size,
                              hipStream_t stream) {
  const float* x   = (const float*)d_in[0];
  const float* Whx = (const float*)d_in[1];
  const float* Whh = (const float*)d_in[2];
  const float* bh  = (const float*)d_in[3];
  const float* Wph = (const float*)d_in[4];
  const float* bp  = (const float*)d_in[5];
  float* out = (float*)d_out;

  unsigned short* hbuf = (unsigned short*)d_ws;
  int* flags = (int*)((char*)d_ws + (size_t)2 * HBUF_HALVES * 2);  // +2 MB

  hipFuncSetAttribute(reinterpret_cast<const void*>(rnn_persistent),
                      hipFuncAttributeMaxDynamicSharedMemorySize, SMEM_BYTES);

  rnn_persistent<<<dim3(GB * GJ), dim3(256), SMEM_BYTES, stream>>>(
      x, Whx, Whh, bh, Wph, bp, out, hbuf, flags);
}

// Round 7
// 2104.498 us; speedup vs baseline: 1.8167x; 1.8167x over previous
//
#include <hip/hip_runtime.h>
#include <stdint.h>

// Persistent-kernel RNN, R7 = R3 body + split-scope sync.
// R6 lesson: XCD-local (sc0) DATA path works (WRITE 264->2.3 MB, FETCH
// 150->20 MB) but sc0-only FLAG polls don't see peer sc0 stores promptly
// (3.4x regression from poll thrash). R7: flags always device-scope
// (sc0 sc1, proven propagation), h stores sc0 when the bg-group verifies
// same-XCD via HW_REG_XCC_ID, h loads always sc0 sc1 (served by the dirty
// L2 line when local; correct at device scope otherwise).

#define BATCH 512
#define SEQ   256
#define HID   1024
#define CLS   128

#define GB 16
#define GJ 16
#define BT 32
#define JT 64
#define WSTR 1028
#define SSTR 1032
#define HSTR 72
#define SMEM_BYTES (JT * WSTR * 2)                 // 131584 B
#define SS_BYTES   (BT * SSTR * 2)                 // 66048
#define RB_OFF     SS_BYTES
#define HS_OFF     (RB_OFF + 8192)
#define HBUF_HALVES (BATCH * HID)                  // 1 MB per buffer (x2)

typedef __attribute__((ext_vector_type(8))) short  bf16x8;
typedef __attribute__((ext_vector_type(4))) short  s16x4;
typedef __attribute__((ext_vector_type(4))) float  f32x4;
typedef __attribute__((ext_vector_type(4))) int    i32x4;

__device__ __forceinline__ unsigned short f2bf(float f) {
  unsigned int u = __float_as_uint(f);
  u = (u + 0x7FFFu + ((u >> 16) & 1u)) >> 16;   // RNE
  return (unsigned short)u;
}
__device__ __forceinline__ float b2f(short h) {
  return __uint_as_float(((unsigned int)(unsigned short)h) << 16);
}

// ---------------- memory ops ----------------
// flags: ALWAYS device scope (sc0 sc1) — proven propagation path.
__device__ __forceinline__ void store_flag_dev(int* p, int v) {
  asm volatile("global_store_dword %0, %1, off sc0 sc1" :: "v"(p), "v"(v) : "memory");
}
// min of 16 peer flags in one round trip (one 64B line), device scope
__device__ __forceinline__ int flags_min16(const int* p) {
  i32x4 f0, f1, f2, f3;
  asm volatile(
    "global_load_dwordx4 %0, %4, off sc0 sc1\n\t"
    "global_load_dwordx4 %1, %4, off offset:16 sc0 sc1\n\t"
    "global_load_dwordx4 %2, %4, off offset:32 sc0 sc1\n\t"
    "global_load_dwordx4 %3, %4, off offset:48 sc0 sc1\n\t"
    "s_waitcnt vmcnt(0)"
    : "=&v"(f0), "=&v"(f1), "=&v"(f2), "=&v"(f3) : "v"(p) : "memory");
  int m = f0.x;
  m = f0.y < m ? f0.y : m;  m = f0.z < m ? f0.z : m;  m = f0.w < m ? f0.w : m;
  m = f1.x < m ? f1.x : m;  m = f1.y < m ? f1.y : m;  m = f1.z < m ? f1.z : m;  m = f1.w < m ? f1.w : m;
  m = f2.x < m ? f2.x : m;  m = f2.y < m ? f2.y : m;  m = f2.z < m ? f2.z : m;  m = f2.w < m ? f2.w : m;
  m = f3.x < m ? f3.x : m;  m = f3.y < m ? f3.y : m;  m = f3.z < m ? f3.z : m;  m = f3.w < m ? f3.w : m;
  return m;
}
__device__ __forceinline__ void flags_minmax16_dev(const int* p, int& mn, int& mx) {
  i32x4 f0, f1, f2, f3;
  asm volatile(
    "global_load_dwordx4 %0, %4, off sc0 sc1\n\t"
    "global_load_dwordx4 %1, %4, off offset:16 sc0 sc1\n\t"
    "global_load_dwordx4 %2, %4, off offset:32 sc0 sc1\n\t"
    "global_load_dwordx4 %3, %4, off offset:48 sc0 sc1\n\t"
    "s_waitcnt vmcnt(0)"
    : "=&v"(f0), "=&v"(f1), "=&v"(f2), "=&v"(f3) : "v"(p) : "memory");
  int a[16] = {f0.x,f0.y,f0.z,f0.w, f1.x,f1.y,f1.z,f1.w,
               f2.x,f2.y,f2.z,f2.w, f3.x,f3.y,f3.z,f3.w};
  mn = a[0]; mx = a[0];
#pragma unroll
  for (int i = 1; i < 16; ++i) { mn = a[i] < mn ? a[i] : mn; mx = a[i] > mx ? a[i] : mx; }
}
// h loads: ALWAYS device scope (bypass L1; served by dirty L2 line when local)
__device__ __forceinline__ void issue4_dev(const void* p, i32x4& a, i32x4& b, i32x4& c, i32x4& d) {
  asm volatile(
    "global_load_dwordx4 %0, %4, off sc0 sc1\n\t"
    "global_load_dwordx4 %1, %4, off offset:128 sc0 sc1\n\t"
    "global_load_dwordx4 %2, %4, off offset:256 sc0 sc1\n\t"
    "global_load_dwordx4 %3, %4, off offset:384 sc0 sc1"
    : "=&v"(a), "=&v"(b), "=&v"(c), "=&v"(d) : "v"(p) : "memory");
}
// h stores: sc0 only when local (stop at XCD L2), sc0 sc1 otherwise
template<bool LP>
__device__ __forceinline__ void g_store16(void* p, i32x4 v) {
  if constexpr (LP)
    asm volatile("global_store_dwordx4 %0, %1, off sc0" :: "v"(p), "v"(v) : "memory");
  else
    asm volatile("global_store_dwordx4 %0, %1, off sc0 sc1" :: "v"(p), "v"(v) : "memory");
}
__device__ __forceinline__ void waitcnt0() {
  asm volatile("s_waitcnt vmcnt(0)" ::: "memory");
}
__device__ __forceinline__ void barrier_lgkm() {
  asm volatile("s_waitcnt lgkmcnt(0)\n\ts_barrier" ::: "memory");
}
#define DEF_WAIT(NAME, N) \
__device__ __forceinline__ void NAME(i32x4& a, i32x4& b, i32x4& c, i32x4& d) { \
  asm volatile("s_waitcnt vmcnt(" #N ")" : "+v"(a), "+v"(b), "+v"(c), "+v"(d) :: "memory"); \
}
DEF_WAIT(wait_vm12, 12)
DEF_WAIT(wait_vm8, 8)
DEF_WAIT(wait_vm4, 4)
DEF_WAIT(wait_vm0, 0)

__device__ __forceinline__ void wr16(short* p, i32x4 v) {
  union { i32x4 i; bf16x8 v8; } u; u.i = v;
  *(bf16x8*)p = u.v8;
}
__device__ __forceinline__ float tanh_fast(float z) {
  float e = __expf(2.f * z);
  return 1.f - 2.f / (e + 1.f);
}

template<int CK>
__device__ __forceinline__ void mfma_chunk(const short* sA0, const bf16x8 (&fB)[2][16],
                                           f32x4 (&acc)[2][2]) {
#pragma unroll
  for (int ks = 0; ks < 8; ++ks) {
    const int kk = CK * 8 + ks;
    bf16x8 a0 = *(const bf16x8*)(sA0 + CK * 256 + ks * 32);
    bf16x8 a1 = *(const bf16x8*)(sA0 + 16 * SSTR + CK * 256 + ks * 32);
#pragma unroll
    for (int nt = 0; nt < 2; ++nt) {
      acc[0][nt] = __builtin_amdgcn_mfma_f32_16x16x32_bf16(a0, fB[nt][kk], acc[0][nt], 0, 0, 0);
      acc[1][nt] = __builtin_amdgcn_mfma_f32_16x16x32_bf16(a1, fB[nt][kk], acc[1][nt], 0, 0, 0);
    }
  }
}

// ---------------- recurrence + head (R3 body, store-scope templated) ----------------
template<bool LP>
__device__ __forceinline__ void rnn_body(
    const float* __restrict__ x, const float* __restrict__ Wph,
    const float* __restrict__ bp, float* __restrict__ out,
    unsigned short* hbuf, int* myflags,
    short* sS, float* rbuf, short* hS,
    const bf16x8 (&fB)[2][16],
    int tid, int bg, int jg, int lane, int npair, int khalf,
    int l15, int quad,
    float whx0, float whx1, float bh0, float bh1,
    int sr, int seg)
{
  const short* sA0 = sS + l15 * SSTR + khalf * 512 + quad * 8;

  for (int t = 0; t < SEQ; ++t) {
    const unsigned short* hin = hbuf + ((t + 1) & 1) * HBUF_HALVES;
    unsigned short*      hout = hbuf + (t & 1) * HBUF_HALVES;

    f32x4 acc[2][2];
#pragma unroll
    for (int mt = 0; mt < 2; ++mt)
#pragma unroll
      for (int nt = 0; nt < 2; ++nt)
        acc[mt][nt] = (f32x4){0.f, 0.f, 0.f, 0.f};

    float xv[2][4];
    {
      const float* xp = x + (bg * BT + quad * 4) * SEQ + t;
#pragma unroll
      for (int r = 0; r < 4; ++r) {
        xv[0][r] = xp[r * SEQ];
        xv[1][r] = xp[(16 + r) * SEQ];
      }
    }

    if (t > 0) {
      if (tid == 0) {
        while (flags_min16(myflags) < t) {}
      }
      __syncthreads();   // full drain: vmcnt==0 entering the issue window

      const char* lbase = (const char*)(hin + (bg * BT + sr) * HID) + seg * 16;
      short* sdst = sS + sr * SSTR + seg * 8;

      i32x4 a0, a1, a2, a3, b0, b1, b2, b3, c0, c1, c2, c3, d0, d1, d2, d3;
      issue4_dev(lbase,        a0, a1, a2, a3);
      issue4_dev(lbase + 512,  b0, b1, b2, b3);
      issue4_dev(lbase + 1024, c0, c1, c2, c3);
      issue4_dev(lbase + 1536, d0, d1, d2, d3);

      wait_vm12(a0, a1, a2, a3);
      wr16(sdst, a0); wr16(sdst + 64, a1); wr16(sdst + 128, a2); wr16(sdst + 192, a3);
      barrier_lgkm();
      if (khalf == 0) mfma_chunk<0>(sA0, fB, acc);

      wait_vm8(b0, b1, b2, b3);
      wr16(sdst + 256, b0); wr16(sdst + 320, b1); wr16(sdst + 384, b2); wr16(sdst + 448, b3);
      barrier_lgkm();
      if (khalf == 0) mfma_chunk<1>(sA0, fB, acc);

      wait_vm4(c0, c1, c2, c3);
      wr16(sdst + 512, c0); wr16(sdst + 576, c1); wr16(sdst + 640, c2); wr16(sdst + 704, c3);
      barrier_lgkm();
      if (khalf == 1) mfma_chunk<0>(sA0, fB, acc);

      wait_vm0(d0, d1, d2, d3);
      wr16(sdst + 768, d0); wr16(sdst + 832, d1); wr16(sdst + 896, d2); wr16(sdst + 960, d3);
      barrier_lgkm();
      if (khalf == 1) mfma_chunk<1>(sA0, fB, acc);
    }

    // cross-wave k-reduce: khalf==1 writes partials, khalf==0 adds + epilogue
    if (khalf == 1) {
#pragma unroll
      for (int mt = 0; mt < 2; ++mt)
#pragma unroll
        for (int nt = 0; nt < 2; ++nt)
          *(f32x4*)(rbuf + ((npair * 4 + mt * 2 + nt) * 64 + lane) * 4) = acc[mt][nt];
    }
    barrier_lgkm();

    if (khalf == 0) {
#pragma unroll
      for (int mt = 0; mt < 2; ++mt)
#pragma unroll
        for (int nt = 0; nt < 2; ++nt) {
          f32x4 p = *(const f32x4*)(rbuf + ((npair * 4 + mt * 2 + nt) * 64 + lane) * 4);
          acc[mt][nt] += p;
        }
#pragma unroll
      for (int mt = 0; mt < 2; ++mt) {
#pragma unroll
        for (int r = 0; r < 4; ++r) {
          const int row = mt * 16 + quad * 4 + r;
          float z0 = acc[mt][0][r] + xv[mt][r] * whx0 + bh0;
          hS[row * HSTR + npair * 32 + l15] = (short)f2bf(tanh_fast(z0));
          float z1 = acc[mt][1][r] + xv[mt][r] * whx1 + bh1;
          hS[row * HSTR + npair * 32 + 16 + l15] = (short)f2bf(tanh_fast(z1));
        }
      }
    }
    barrier_lgkm();

    // coalesced 16B store of the 32x64 h tile (sc0 when local)
    {
      union { bf16x8 v8; i32x4 i; } u;
      u.v8 = *(const bf16x8*)(hS + sr * HSTR + seg * 8);
      g_store16<LP>(hout + (bg * BT + sr) * HID + jg * JT + seg * 8, u.i);
    }
    waitcnt0();          // acked at L2 (local) / IC (fallback)
    barrier_lgkm();
    if (tid == 0) store_flag_dev(myflags + jg, t + 1);
  }

  // ---- output head ----
  if (tid == 0) {
    while (flags_min16(myflags) < SEQ) {}
  }
  __syncthreads();

  const unsigned short* hlast = hbuf + ((SEQ - 1) & 1) * HBUF_HALVES;
  {
    const char* lbase = (const char*)(hlast + (bg * BT + sr) * HID) + seg * 16;
    short* sdst = sS + sr * SSTR + seg * 8;
    i32x4 p0, p1, p2, p3;
#pragma unroll
    for (int c = 0; c < 4; ++c) {
      issue4_dev(lbase + c * 512, p0, p1, p2, p3);
      waitcnt0();
      wr16(sdst + c * 256, p0); wr16(sdst + c * 256 + 64, p1);
      wr16(sdst + c * 256 + 128, p2); wr16(sdst + c * 256 + 192, p3);
    }
  }
  __syncthreads();

  {
    const int cg = jg * 8 + (tid & 7);
    const int hr = tid >> 3;
    float acc = 0.f;
    const float* wp = Wph + cg * HID;
    const short* hs = sS + hr * SSTR;
#pragma unroll 8
    for (int k4 = 0; k4 < 256; ++k4) {
      float4 w  = *(const float4*)(wp + k4 * 4);
      s16x4 hv  = *(const s16x4*)(hs + k4 * 4);
      acc += b2f(hv.x) * w.x + b2f(hv.y) * w.y + b2f(hv.z) * w.z + b2f(hv.w) * w.w;
    }
    out[(bg * BT + hr) * CLS + cg] = acc + bp[cg];
  }
}

__global__ void __launch_bounds__(256, 1)
rnn_persistent(const float* __restrict__ x, const float* __restrict__ Whx,
               const float* __restrict__ Whh, const float* __restrict__ bh,
               const float* __restrict__ Wph, const float* __restrict__ bp,
               float* __restrict__ out, unsigned short* hbuf, int* flags)
{
  extern __shared__ short smem[];
  short* sW   = smem;
  short* sS   = smem;
  float* rbuf = (float*)((char*)smem + RB_OFF);
  short* hS   = (short*)((char*)smem + HS_OFF);
  __shared__ int s_local;

  const int tid  = threadIdx.x;
  const int bg   = blockIdx.x & 15;
  const int jg   = blockIdx.x >> 4;
  const int lane = tid & 63;
  const int wv   = tid >> 6;
  const int l15  = lane & 15;
  const int quad = lane >> 4;
  const int npair = wv & 1;
  const int khalf = wv >> 1;

  // flag line: ints [0,16) step flags, ints [16,32) XCC-id exchange
  int* myflags = flags + bg * 64;
  int* xline   = myflags + 16;

  if (tid == 0) {
    int xcd;
    asm volatile("s_getreg_b32 %0, hwreg(HW_REG_XCC_ID)" : "=s"(xcd));
    store_flag_dev(xline + jg, 4096 + xcd);
  }

  // ---- stage W_hh slice into LDS as bf16 (init only) ----
  {
    const int jr = tid >> 2;
    const int kq = tid & 3;
    const float* src = Whh + (jg * JT + jr) * HID + kq * 256;
    short* dst = sW + jr * WSTR + kq * 256;
#pragma unroll 4
    for (int i = 0; i < 64; ++i) {
      float4 f = *(const float4*)(src + i * 4);
      s16x4 h4;
      h4.x = (short)f2bf(f.x); h4.y = (short)f2bf(f.y);
      h4.z = (short)f2bf(f.z); h4.w = (short)f2bf(f.w);
      *(s16x4*)(dst + i * 4) = h4;
    }
  }
  __syncthreads();

  // ---- preload B-fragments into registers (128 VGPR/wave) ----
  bf16x8 fB[2][16];
#pragma unroll
  for (int nt = 0; nt < 2; ++nt) {
    const short* bp_ = sW + (npair * 32 + nt * 16 + l15) * WSTR + khalf * 512 + quad * 8;
#pragma unroll
    for (int kk = 0; kk < 16; ++kk) {
      union { bf16x8 v8; s16x4 h[2]; } u;
      u.h[0] = *(const s16x4*)(bp_ + kk * 32);
      u.h[1] = *(const s16x4*)(bp_ + kk * 32 + 4);
      fB[nt][kk] = u.v8;
    }
  }

  // ---- finish XCC exchange: whole bg-group on one XCD? ----
  if (tid == 0) {
    int mn, mx;
    do { flags_minmax16_dev(xline, mn, mx); } while (mn < 4096);
    s_local = (mn == mx) ? 1 : 0;
  }
  __syncthreads();   // also covers sW -> sS overlay transition
  const bool local = (s_local != 0);

  const int jb0 = jg * JT + npair * 32;
  const float whx0 = Whx[jb0 + l15];
  const float whx1 = Whx[jb0 + 16 + l15];
  const float bh0  = bh[jb0 + l15];
  const float bh1  = bh[jb0 + 16 + l15];
  const int sr  = tid >> 3;
  const int seg = tid & 7;

  if (local)
    rnn_body<true>(x, Wph, bp, out, hbuf, myflags, sS, rbuf, hS, fB,
                   tid, bg, jg, lane, npair, khalf, l15, quad,
                   whx0, whx1, bh0, bh1, sr, seg);
  else
    rnn_body<false>(x, Wph, bp, out, hbuf, myflags, sS, rbuf, hS, fB,
                    tid, bg, jg, lane, npair, khalf, l15, quad,
                    whx0, whx1, bh0, bh1, sr, seg);
}

extern "C" void kernel_launch(void* const* d_in, const int* in_sizes, int n_in,
                              void* d_out, int out_size, void* d_ws, size_t ws_size,
                              hipStream_t stream) {
  const float* x   = (const float*)d_in[0];
  const float* Whx = (const float*)d_in[1];
  const float* Whh = (const float*)d_in[2];
  const float* bh  = (const float*)d_in[3];
  const float* Wph = (const float*)d_in[4];
  const float* bp  = (const float*)d_in[5];
  float* out = (float*)d_out;

  unsigned short* hbuf = (unsigned short*)d_ws;
  int* flags = (int*)((char*)d_ws + (size_t)2 * HBUF_HALVES * 2);  // +2 MB

  hipFuncSetAttribute(reinterpret_cast<const void*>(rnn_persistent),
                      hipFuncAttributeMaxDynamicSharedMemorySize, SMEM_BYTES);

  rnn_persistent<<<dim3(GB * GJ), dim3(256), SMEM_BYTES, stream>>>(
      x, Whx, Whh, bh, Wph, bp, out, hbuf, flags);
}

// Round 8
// 1278.142 us; speedup vs baseline: 2.9912x; 1.6465x over previous
//
#include <hip/hip_runtime.h>
#include <stdint.h>

// Persistent-kernel RNN, R8 = R3 body + elastic pipeline.
// Pure device-scope (sc0 sc1) everywhere — R4..R7 scope experiments all
// regressed (dirty-L2 forward penalty + 32ms outliers). New: 4-deep h ring
// buffer + per-chunk read gates (chunk c of step t needs only flags[4c..4c+3]
// >= t) so wgs absorb peer jitter instead of paying max-of-16 every step.
// Write-safety: buffer t&3 may be overwritten once min16(flags) >= t-2.

#define BATCH 512
#define SEQ   256
#define HID   1024
#define CLS   128

#define GB 16
#define GJ 16
#define BT 32
#define JT 64
#define WSTR 1028
#define SSTR 1032
#define HSTR 72
#define SMEM_BYTES (JT * WSTR * 2)                 // 131584 B
#define RB_OFF  (BT * SSTR * 2)                    // 66048
#define HS_OFF  (RB_OFF + 8192)
#define HBUF_HALVES (BATCH * HID)                  // 1 MB per buffer, x4 ring

typedef __attribute__((ext_vector_type(8))) short  bf16x8;
typedef __attribute__((ext_vector_type(4))) short  s16x4;
typedef __attribute__((ext_vector_type(4))) float  f32x4;
typedef __attribute__((ext_vector_type(4))) int    i32x4;

__device__ __forceinline__ unsigned short f2bf(float f) {
  unsigned int u = __float_as_uint(f);
  u = (u + 0x7FFFu + ((u >> 16) & 1u)) >> 16;   // RNE
  return (unsigned short)u;
}
__device__ __forceinline__ float b2f(short h) {
  return __uint_as_float(((unsigned int)(unsigned short)h) << 16);
}

// ---- device-scope ops (sc0 sc1 = IC coherence point) ----
__device__ __forceinline__ void store_flag_dev(int* p, int v) {
  asm volatile("global_store_dword %0, %1, off sc0 sc1" :: "v"(p), "v"(v) : "memory");
}
__device__ __forceinline__ void store16_dev(void* p, i32x4 v) {
  asm volatile("global_store_dwordx4 %0, %1, off sc0 sc1" :: "v"(p), "v"(v) : "memory");
}
__device__ __forceinline__ void issue4_dev(const void* p, i32x4& a, i32x4& b, i32x4& c, i32x4& d) {
  asm volatile(
    "global_load_dwordx4 %0, %4, off sc0 sc1\n\t"
    "global_load_dwordx4 %1, %4, off offset:128 sc0 sc1\n\t"
    "global_load_dwordx4 %2, %4, off offset:256 sc0 sc1\n\t"
    "global_load_dwordx4 %3, %4, off offset:384 sc0 sc1"
    : "=&v"(a), "=&v"(b), "=&v"(c), "=&v"(d) : "v"(p) : "memory");
}
__device__ __forceinline__ void waitcnt0() {
  asm volatile("s_waitcnt vmcnt(0)" ::: "memory");
}
__device__ __forceinline__ void barrier_lgkm() {
  asm volatile("s_waitcnt lgkmcnt(0)\n\ts_barrier" ::: "memory");
}
#define DEF_WAIT(NAME, N) \
__device__ __forceinline__ void NAME(i32x4& a, i32x4& b, i32x4& c, i32x4& d) { \
  asm volatile("s_waitcnt vmcnt(" #N ")" : "+v"(a), "+v"(b), "+v"(c), "+v"(d) :: "memory"); \
}
DEF_WAIT(wait_vm12, 12)
DEF_WAIT(wait_vm8, 8)
DEF_WAIT(wait_vm4, 4)
DEF_WAIT(wait_vm0, 0)

// full 16-flag view: per-chunk mins (4 peers each) + global min. One 64B
// broadcast load per poll (all lanes same address -> 1 req/wave).
struct FlagView { int mc0, mc1, mc2, mc3, m16; };
__device__ __forceinline__ int min4(i32x4 f) {
  int m = f.x;
  m = f.y < m ? f.y : m; m = f.z < m ? f.z : m; m = f.w < m ? f.w : m;
  return m;
}
__device__ __forceinline__ FlagView flags_view(const int* p) {
  i32x4 f0, f1, f2, f3;
  asm volatile(
    "global_load_dwordx4 %0, %4, off sc0 sc1\n\t"
    "global_load_dwordx4 %1, %4, off offset:16 sc0 sc1\n\t"
    "global_load_dwordx4 %2, %4, off offset:32 sc0 sc1\n\t"
    "global_load_dwordx4 %3, %4, off offset:48 sc0 sc1\n\t"
    "s_waitcnt vmcnt(0)"
    : "=&v"(f0), "=&v"(f1), "=&v"(f2), "=&v"(f3) : "v"(p) : "memory");
  FlagView v;
  v.mc0 = min4(f0); v.mc1 = min4(f1); v.mc2 = min4(f2); v.mc3 = min4(f3);
  int m = v.mc0;
  m = v.mc1 < m ? v.mc1 : m; m = v.mc2 < m ? v.mc2 : m; m = v.mc3 < m ? v.mc3 : m;
  v.m16 = m;
  return v;
}

__device__ __forceinline__ void wr16(short* p, i32x4 v) {
  union { i32x4 i; bf16x8 v8; } u; u.i = v;
  *(bf16x8*)p = u.v8;
}
__device__ __forceinline__ float tanh_fast(float z) {
  float e = __expf(2.f * z);
  return 1.f - 2.f / (e + 1.f);
}

template<int CK>
__device__ __forceinline__ void mfma_chunk(const short* sA0, const bf16x8 (&fB)[2][16],
                                           f32x4 (&acc)[2][2]) {
#pragma unroll
  for (int ks = 0; ks < 8; ++ks) {
    const int kk = CK * 8 + ks;
    bf16x8 a0 = *(const bf16x8*)(sA0 + CK * 256 + ks * 32);
    bf16x8 a1 = *(const bf16x8*)(sA0 + 16 * SSTR + CK * 256 + ks * 32);
#pragma unroll
    for (int nt = 0; nt < 2; ++nt) {
      acc[0][nt] = __builtin_amdgcn_mfma_f32_16x16x32_bf16(a0, fB[nt][kk], acc[0][nt], 0, 0, 0);
      acc[1][nt] = __builtin_amdgcn_mfma_f32_16x16x32_bf16(a1, fB[nt][kk], acc[1][nt], 0, 0, 0);
    }
  }
}

__global__ void __launch_bounds__(256, 1)
rnn_persistent(const float* __restrict__ x, const float* __restrict__ Whx,
               const float* __restrict__ Whh, const float* __restrict__ bh,
               const float* __restrict__ Wph, const float* __restrict__ bp,
               float* __restrict__ out, unsigned short* hbuf, int* flags)
{
  extern __shared__ short smem[];
  short* sW   = smem;                          // init-only overlay
  short* sS   = smem;                          // loop-time h stage
  float* rbuf = (float*)((char*)smem + RB_OFF);
  short* hS   = (short*)((char*)smem + HS_OFF);

  const int tid  = threadIdx.x;
  const int bg   = blockIdx.x & 15;
  const int jg   = blockIdx.x >> 4;
  const int lane = tid & 63;
  const int wv   = tid >> 6;
  const int l15  = lane & 15;
  const int quad = lane >> 4;
  const int npair = wv & 1;
  const int khalf = wv >> 1;

  // ---- stage W_hh slice into LDS as bf16 (init only) ----
  {
    const int jr = tid >> 2;
    const int kq = tid & 3;
    const float* src = Whh + (jg * JT + jr) * HID + kq * 256;
    short* dst = sW + jr * WSTR + kq * 256;
#pragma unroll 4
    for (int i = 0; i < 64; ++i) {
      float4 f = *(const float4*)(src + i * 4);
      s16x4 h4;
      h4.x = (short)f2bf(f.x); h4.y = (short)f2bf(f.y);
      h4.z = (short)f2bf(f.z); h4.w = (short)f2bf(f.w);
      *(s16x4*)(dst + i * 4) = h4;
    }
  }
  __syncthreads();

  // ---- preload B-fragments into registers (128 VGPR/wave) ----
  bf16x8 fB[2][16];
#pragma unroll
  for (int nt = 0; nt < 2; ++nt) {
    const short* bp_ = sW + (npair * 32 + nt * 16 + l15) * WSTR + khalf * 512 + quad * 8;
#pragma unroll
    for (int kk = 0; kk < 16; ++kk) {
      union { bf16x8 v8; s16x4 h[2]; } u;
      u.h[0] = *(const s16x4*)(bp_ + kk * 32);
      u.h[1] = *(const s16x4*)(bp_ + kk * 32 + 4);
      fB[nt][kk] = u.v8;
    }
  }
  __syncthreads();   // sW dead; sS overlay live

  const int jb0 = jg * JT + npair * 32;
  const float whx0 = Whx[jb0 + l15];
  const float whx1 = Whx[jb0 + 16 + l15];
  const float bh0  = bh[jb0 + l15];
  const float bh1  = bh[jb0 + 16 + l15];
  const int sr  = tid >> 3;
  const int seg = tid & 7;

  int* myflags = flags + bg * 64;
  const short* sA0 = sS + l15 * SSTR + khalf * 512 + quad * 8;

  for (int t = 0; t < SEQ; ++t) {
    const unsigned short* hin = hbuf + ((t + 3) & 3) * HBUF_HALVES;  // buffer of t-1
    unsigned short*      hout = hbuf + (t & 3) * HBUF_HALVES;

    f32x4 acc[2][2];
#pragma unroll
    for (int mt = 0; mt < 2; ++mt)
#pragma unroll
      for (int nt = 0; nt < 2; ++nt)
        acc[mt][nt] = (f32x4){0.f, 0.f, 0.f, 0.f};

    float xv[2][4];
    {
      const float* xp = x + (bg * BT + quad * 4) * SEQ + t;
#pragma unroll
      for (int r = 0; r < 4; ++r) {
        xv[0][r] = xp[r * SEQ];
        xv[1][r] = xp[(16 + r) * SEQ];
      }
    }

    bool wg_ok = (t < 3);   // write-gate: buffer t&3 unread before t==3

    if (t > 0) {
      const char* lbase = (const char*)(hin + (bg * BT + sr) * HID) + seg * 16;
      short* sdst = sS + sr * SSTR + seg * 8;

      // gate chunk 0 (peers 0..3); poll also snapshots all other gates
      FlagView fv = flags_view(myflags);
      while (fv.mc0 < t) fv = flags_view(myflags);
      wg_ok = wg_ok || (fv.m16 >= t - 2);

      if (fv.m16 >= t) {
        // FAST PATH (steady state): all gates pass -> exact R3 vmcnt ladder
        i32x4 a0, a1, a2, a3, b0, b1, b2, b3, c0, c1, c2, c3, d0, d1, d2, d3;
        issue4_dev(lbase,        a0, a1, a2, a3);
        issue4_dev(lbase + 512,  b0, b1, b2, b3);
        issue4_dev(lbase + 1024, c0, c1, c2, c3);
        issue4_dev(lbase + 1536, d0, d1, d2, d3);

        wait_vm12(a0, a1, a2, a3);
        wr16(sdst, a0); wr16(sdst + 64, a1); wr16(sdst + 128, a2); wr16(sdst + 192, a3);
        barrier_lgkm();
        if (khalf == 0) mfma_chunk<0>(sA0, fB, acc);

        wait_vm8(b0, b1, b2, b3);
        wr16(sdst + 256, b0); wr16(sdst + 320, b1); wr16(sdst + 384, b2); wr16(sdst + 448, b3);
        barrier_lgkm();
        if (khalf == 0) mfma_chunk<1>(sA0, fB, acc);

        wait_vm4(c0, c1, c2, c3);
        wr16(sdst + 512, c0); wr16(sdst + 576, c1); wr16(sdst + 640, c2); wr16(sdst + 704, c3);
        barrier_lgkm();
        if (khalf == 1) mfma_chunk<0>(sA0, fB, acc);

        wait_vm0(d0, d1, d2, d3);
        wr16(sdst + 768, d0); wr16(sdst + 832, d1); wr16(sdst + 896, d2); wr16(sdst + 960, d3);
        barrier_lgkm();
        if (khalf == 1) mfma_chunk<1>(sA0, fB, acc);
      } else {
        // SLOW PATH (straggler among peers): in-order per-chunk gating.
        // Same barrier count (4) as fast path -> mixed per-thread paths align.
        i32x4 p0, p1, p2, p3;
        issue4_dev(lbase, p0, p1, p2, p3);
        wait_vm0(p0, p1, p2, p3);
        wr16(sdst, p0); wr16(sdst + 64, p1); wr16(sdst + 128, p2); wr16(sdst + 192, p3);
        barrier_lgkm();
        if (khalf == 0) mfma_chunk<0>(sA0, fB, acc);

        while (fv.mc1 < t) { fv = flags_view(myflags); wg_ok = wg_ok || (fv.m16 >= t - 2); }
        issue4_dev(lbase + 512, p0, p1, p2, p3);
        wait_vm0(p0, p1, p2, p3);
        wr16(sdst + 256, p0); wr16(sdst + 320, p1); wr16(sdst + 384, p2); wr16(sdst + 448, p3);
        barrier_lgkm();
        if (khalf == 0) mfma_chunk<1>(sA0, fB, acc);

        while (fv.mc2 < t) { fv = flags_view(myflags); wg_ok = wg_ok || (fv.m16 >= t - 2); }
        issue4_dev(lbase + 1024, p0, p1, p2, p3);
        wait_vm0(p0, p1, p2, p3);
        wr16(sdst + 512, p0); wr16(sdst + 576, p1); wr16(sdst + 640, p2); wr16(sdst + 704, p3);
        barrier_lgkm();
        if (khalf == 1) mfma_chunk<0>(sA0, fB, acc);

        while (fv.mc3 < t) { fv = flags_view(myflags); wg_ok = wg_ok || (fv.m16 >= t - 2); }
        issue4_dev(lbase + 1536, p0, p1, p2, p3);
        wait_vm0(p0, p1, p2, p3);
        wr16(sdst + 768, p0); wr16(sdst + 832, p1); wr16(sdst + 896, p2); wr16(sdst + 960, p3);
        barrier_lgkm();
        if (khalf == 1) mfma_chunk<1>(sA0, fB, acc);
      }
    }

    // cross-wave k-reduce: khalf==1 writes partials, khalf==0 adds + epilogue
    if (khalf == 1) {
#pragma unroll
      for (int mt = 0; mt < 2; ++mt)
#pragma unroll
        for (int nt = 0; nt < 2; ++nt)
          *(f32x4*)(rbuf + ((npair * 4 + mt * 2 + nt) * 64 + lane) * 4) = acc[mt][nt];
    }
    barrier_lgkm();

    if (khalf == 0) {
#pragma unroll
      for (int mt = 0; mt < 2; ++mt)
#pragma unroll
        for (int nt = 0; nt < 2; ++nt) {
          f32x4 p = *(const f32x4*)(rbuf + ((npair * 4 + mt * 2 + nt) * 64 + lane) * 4);
          acc[mt][nt] += p;
        }
#pragma unroll
      for (int mt = 0; mt < 2; ++mt) {
#pragma unroll
        for (int r = 0; r < 4; ++r) {
          const int row = mt * 16 + quad * 4 + r;
          float z0 = acc[mt][0][r] + xv[mt][r] * whx0 + bh0;
          hS[row * HSTR + npair * 32 + l15] = (short)f2bf(tanh_fast(z0));
          float z1 = acc[mt][1][r] + xv[mt][r] * whx1 + bh1;
          hS[row * HSTR + npair * 32 + 16 + l15] = (short)f2bf(tanh_fast(z1));
        }
      }
    }
    barrier_lgkm();

    // write-gate: ring slot t&3 reusable once all peers finished step t-3
    if (!wg_ok) {
      FlagView fv2 = flags_view(myflags);
      while (fv2.m16 < t - 2) fv2 = flags_view(myflags);
    }

    // coalesced 16B store of the 32x64 h tile
    {
      union { bf16x8 v8; i32x4 i; } u;
      u.v8 = *(const bf16x8*)(hS + sr * HSTR + seg * 8);
      store16_dev(hout + (bg * BT + sr) * HID + jg * JT + seg * 8, u.i);
    }
    waitcnt0();          // h store acked at IC
    barrier_lgkm();      // all threads acked
    if (tid == 0) store_flag_dev(myflags + jg, t + 1);
  }

  // ---- output head ----
  {
    FlagView fv = flags_view(myflags);
    while (fv.m16 < SEQ) fv = flags_view(myflags);
  }
  __syncthreads();

  const unsigned short* hlast = hbuf + ((SEQ - 1) & 3) * HBUF_HALVES;
  {
    const char* lbase = (const char*)(hlast + (bg * BT + sr) * HID) + seg * 16;
    short* sdst = sS + sr * SSTR + seg * 8;
    i32x4 p0, p1, p2, p3;
#pragma unroll
    for (int c = 0; c < 4; ++c) {
      issue4_dev(lbase + c * 512, p0, p1, p2, p3);
      waitcnt0();
      wr16(sdst + c * 256, p0); wr16(sdst + c * 256 + 64, p1);
      wr16(sdst + c * 256 + 128, p2); wr16(sdst + c * 256 + 192, p3);
    }
  }
  __syncthreads();

  {
    const int cg = jg * 8 + (tid & 7);
    const int hr = tid >> 3;
    float acc = 0.f;
    const float* wp = Wph + cg * HID;
    const short* hs = sS + hr * SSTR;
#pragma unroll 8
    for (int k4 = 0; k4 < 256; ++k4) {
      float4 w  = *(const float4*)(wp + k4 * 4);
      s16x4 hv  = *(const s16x4*)(hs + k4 * 4);
      acc += b2f(hv.x) * w.x + b2f(hv.y) * w.y + b2f(hv.z) * w.z + b2f(hv.w) * w.w;
    }
    out[(bg * BT + hr) * CLS + cg] = acc + bp[cg];
  }
}

extern "C" void kernel_launch(void* const* d_in, const int* in_sizes, int n_in,
                              void* d_out, int out_size, void* d_ws, size_t ws_size,
                              hipStream_t stream) {
  const float* x   = (const float*)d_in[0];
  const float* Whx = (const float*)d_in[1];
  const float* Whh = (const float*)d_in[2];
  const float* bh  = (const float*)d_in[3];
  const float* Wph = (const float*)d_in[4];
  const float* bp  = (const float*)d_in[5];
  float* out = (float*)d_out;

  // ws: 4 x 1 MB h ring, then flag lines (16 groups x 64 ints)
  unsigned short* hbuf = (unsigned short*)d_ws;
  int* flags = (int*)((char*)d_ws + (size_t)4 * HBUF_HALVES * 2);

  hipFuncSetAttribute(reinterpret_cast<const void*>(rnn_persistent),
                      hipFuncAttributeMaxDynamicSharedMemorySize, SMEM_BYTES);

  rnn_persistent<<<dim3(GB * GJ), dim3(256), SMEM_BYTES, stream>>>(
      x, Whx, Whh, bh, Wph, bp, out, hbuf, flags);
}